// Round 3
// baseline (740.346 us; speedup 1.0000x reference)
//
#include <hip/hip_runtime.h>
#include <stdint.h>

typedef __attribute__((ext_vector_type(4))) float f32x4;
typedef __attribute__((ext_vector_type(8))) __bf16 bf16x8;

// ---------- helpers ----------
__device__ __forceinline__ unsigned short f2bf(float f) {
  union { float f; uint32_t u; } v; v.f = f;
  uint32_t u = v.u;
  return (unsigned short)((u + 0x7FFFu + ((u >> 16) & 1u)) >> 16);
}
__device__ __forceinline__ float bflo(uint32_t u) {
  union { uint32_t u; float f; } v; v.u = u << 16; return v.f;
}
__device__ __forceinline__ float bfhi(uint32_t u) {
  union { uint32_t u; float f; } v; v.u = u & 0xffff0000u; return v.f;
}

__device__ __forceinline__ void async_copy16(void* lds, const void* g) {
  __builtin_amdgcn_global_load_lds(
      (const __attribute__((address_space(1))) void*)g,
      (__attribute__((address_space(3))) void*)lds,
      16, 0, 0);
}

// ---------- f32 -> bf16 convert (flat) ----------
__global__ void cvt_f32_bf16(const float* __restrict__ in,
                             uint32_t* __restrict__ out, int n) {
  int i = blockIdx.x * blockDim.x + threadIdx.x;
  int idx = i * 8;
  if (idx >= n) return;
  float4 a = *(const float4*)(in + idx);
  float4 b = *(const float4*)(in + idx + 4);
  uint4 o;
  o.x = f2bf(a.x) | ((uint32_t)f2bf(a.y) << 16);
  o.y = f2bf(a.z) | ((uint32_t)f2bf(a.w) << 16);
  o.z = f2bf(b.x) | ((uint32_t)f2bf(b.y) << 16);
  o.w = f2bf(b.z) | ((uint32_t)f2bf(b.w) << 16);
  *(uint4*)(out + i * 4) = o;
}

// ---------- f32 (R x C) -> bf16 transposed (C x R) ----------
__global__ void transpose_to_bf16(const float* __restrict__ in,
                                  unsigned short* __restrict__ out,
                                  int R, int C) {
  __shared__ float tile[32][33];
  int c0 = blockIdx.x * 32, r0 = blockIdx.y * 32;
  int tx = threadIdx.x, ty = threadIdx.y;   // 32 x 8
  #pragma unroll
  for (int rr = 0; rr < 32; rr += 8)
    tile[ty + rr][tx] = in[(size_t)(r0 + ty + rr) * C + c0 + tx];
  __syncthreads();
  #pragma unroll
  for (int rr = 0; rr < 32; rr += 8)
    out[(size_t)(c0 + ty + rr) * R + r0 + tx] = f2bf(tile[tx][ty + rr]);
}

// ---------- init d_out with broadcast bias (for split-K atomic GEMM) ----------
__global__ void init_out(float* __restrict__ out, const float* __restrict__ bo) {
  int i = blockIdx.x * blockDim.x + threadIdx.x;   // one float4 per thread
  int c = (i & 127) * 4;                            // N=512 -> 128 float4/row
  float4 b = *(const float4*)(bo + c);
  *(float4*)(out + (size_t)i * 4) = b;
}

// ---------- 256x256 8-wave 8-phase GEMM ----------
// C(MxN) = A(MxK) @ Bt(NxK)^T [+ bias].  A,Bt bf16 row-major.
// Grid: 1-D, Mt*Nt*KC blocks (must be %8==0 for the XCD swizzle).
// NK K-tiles of 64 per K-chunk. ATOMIC: f32 atomicAdd into pre-initialized C.
// LDS 128 KiB: [buf 0/1][A 32K | B 32K], rows*128B linear, read-side XOR swizzle
// kc ^= (row&7) with inverse-permuted global staging source (rule #21).
template <int NK, bool ATOMIC>
__global__ __launch_bounds__(512, 2) void gemm8(
    const unsigned short* __restrict__ A,
    const unsigned short* __restrict__ Bt,
    const float* __restrict__ bias,
    void* __restrict__ Cout,
    int Mt, int Nt, int KC, int Kfull) {
  __shared__ unsigned short lds[2 * 2 * 256 * 64];   // 131072 B

  // bijective XCD swizzle (nwg % 8 == 0 by construction)
  const int nwg = Mt * Nt * KC;
  const int cpx = nwg >> 3;
  const int bid = blockIdx.x;
  const int nb = (bid & 7) * cpx + (bid >> 3);
  const int bm = nb % Mt;
  const int rest = nb / Mt;
  const int bn = rest % Nt;
  const int kc = rest / Nt;
  const int N = Nt * 256;

  const int tid = threadIdx.x;
  const int wv = tid >> 6, ln = tid & 63;
  const int wm = wv >> 2, wn = wv & 3;     // 2 M-waves x 4 N-waves
  const size_t koff = (size_t)kc * (NK * 64);

  f32x4 acc[8][4] = {};

  // stage one half-tile (mat 0=A,1=B; h = M/N half; t = K-tile) : 2 loads/thread
  auto stage_half = [&](int mat, int h, int t) {
    const unsigned short* src = mat ? Bt : A;
    const int rb = mat ? bn * 256 : bm * 256;
    #pragma unroll
    for (int r = 0; r < 2; ++r) {
      const int lr = h * 128 + r * 64 + wv * 8 + (ln >> 3);
      const int kcs = (ln & 7) ^ (lr & 7);           // inverse-permuted source
      const unsigned short* g =
          src + (size_t)(rb + lr) * Kfull + koff + t * 64 + kcs * 8;
      char* dst = (char*)lds + (size_t)(t & 1) * 65536 + mat * 32768 +
                  (h * 128 + r * 64 + wv * 8) * 128;   // wave-uniform + lane*16
      async_copy16(dst, g);
    }
  };

  // prologue: K-tile 0 fully staged
  stage_half(0, 0, 0); stage_half(1, 0, 0);
  stage_half(0, 1, 0); stage_half(1, 1, 0);
  asm volatile("s_waitcnt vmcnt(0)" ::: "memory");
  __builtin_amdgcn_sched_barrier(0);
  __builtin_amdgcn_s_barrier();

  for (int t = 0; t < NK; ++t) {
    const char* buf = (const char*)lds + (size_t)(t & 1) * 65536;
    #pragma unroll
    for (int ph = 0; ph < 4; ++ph) {
      const int mh = ph >> 1, nh = ph & 1;   // C-quadrant
      // ds-read the quadrant's fragments (12 x ds_read_b128, conflict-free)
      bf16x8 af[4][2], bfb[2][2];
      #pragma unroll
      for (int f = 0; f < 4; ++f) {
        const int lr = wm * 128 + (mh * 4 + f) * 16 + (ln & 15);
        #pragma unroll
        for (int s = 0; s < 2; ++s) {
          const int kq = s * 4 + (ln >> 4);
          af[f][s] = *(const bf16x8*)(buf + lr * 128 + ((kq ^ (lr & 7)) * 16));
        }
      }
      #pragma unroll
      for (int gq = 0; gq < 2; ++gq) {
        const int lr = wn * 64 + (nh * 2 + gq) * 16 + (ln & 15);
        #pragma unroll
        for (int s = 0; s < 2; ++s) {
          const int kq = s * 4 + (ln >> 4);
          bfb[gq][s] =
              *(const bf16x8*)(buf + 32768 + lr * 128 + ((kq ^ (lr & 7)) * 16));
        }
      }
      // prefetch one half-tile of K-tile t+1 (other LDS buffer -> no race)
      if (t < NK - 1) stage_half(ph & 1, ph >> 1, t + 1);

      __builtin_amdgcn_s_barrier();
      __builtin_amdgcn_sched_barrier(0);
      __builtin_amdgcn_s_setprio(1);
      #pragma unroll
      for (int f = 0; f < 4; ++f)
        #pragma unroll
        for (int gq = 0; gq < 2; ++gq)
          #pragma unroll
          for (int s = 0; s < 2; ++s)
            // swapped operands: acc lane = M-row, reg = N-col (packed stores)
            acc[mh * 4 + f][nh * 2 + gq] = __builtin_amdgcn_mfma_f32_16x16x32_bf16(
                bfb[gq][s], af[f][s], acc[mh * 4 + f][nh * 2 + gq], 0, 0, 0);
      __builtin_amdgcn_s_setprio(0);
      __builtin_amdgcn_sched_barrier(0);
      if (ph < 3) __builtin_amdgcn_s_barrier();
    }
    // K-tile boundary: staged loads for t+1 had 4 phases to land -> cheap drain
    asm volatile("s_waitcnt vmcnt(0)" ::: "memory");
    __builtin_amdgcn_sched_barrier(0);
    __builtin_amdgcn_s_barrier();
  }

  // epilogue: lane = M-row (ln&15), reg r = N-col (+r)
  const int m0 = bm * 256 + wm * 128 + (ln & 15);
  const int n0 = bn * 256 + wn * 64 + ((ln >> 4) << 2);
  if (ATOMIC) {
    float* C = (float*)Cout;
    #pragma unroll
    for (int f = 0; f < 8; ++f) {
      const int row = m0 + f * 16;
      #pragma unroll
      for (int g = 0; g < 4; ++g) {
        const int col = n0 + g * 16;
        #pragma unroll
        for (int r = 0; r < 4; ++r)
          atomicAdd(&C[(size_t)row * N + col + r], acc[f][g][r]);
      }
    }
  } else {
    unsigned short* C = (unsigned short*)Cout;
    #pragma unroll
    for (int f = 0; f < 8; ++f) {
      const int row = m0 + f * 16;
      #pragma unroll
      for (int g = 0; g < 4; ++g) {
        const int col = n0 + g * 16;
        float4 bv = *(const float4*)(bias + col);
        uint2 o;
        o.x = f2bf(acc[f][g][0] + bv.x) | ((uint32_t)f2bf(acc[f][g][1] + bv.y) << 16);
        o.y = f2bf(acc[f][g][2] + bv.z) | ((uint32_t)f2bf(acc[f][g][3] + bv.w) << 16);
        *(uint2*)(C + (size_t)row * N + col) = o;
      }
    }
  }
}

// ---------- energy + mask + softmax -> P (f32, 8192 x 64) ----------
__global__ __launch_bounds__(256) void energy_kernel(
    const unsigned short* __restrict__ Q,
    const unsigned short* __restrict__ Kb,
    const int* __restrict__ mask,
    float* __restrict__ P) {
  const int wave = threadIdx.x >> 6, lane = threadIdx.x & 63;
  const int t = blockIdx.x * 4 + wave;
  const unsigned short* Qr = Q + (size_t)t * 4096;
  const unsigned short* Kr = Kb + (size_t)t * 4096;
  const int i = lane >> 3, j = lane & 7;

  float e = 0.f;
  #pragma unroll 4
  for (int d = 0; d < 512; d += 8) {
    uint4 q4 = *(const uint4*)(Qr + i * 512 + d);
    uint4 k4 = *(const uint4*)(Kr + j * 512 + d);
    e += bflo(q4.x) * bflo(k4.x) + bfhi(q4.x) * bfhi(k4.x);
    e += bflo(q4.y) * bflo(k4.y) + bfhi(q4.y) * bfhi(k4.y);
    e += bflo(q4.z) * bflo(k4.z) + bfhi(q4.z) * bfhi(k4.z);
    e += bflo(q4.w) * bflo(k4.w) + bfhi(q4.w) * bfhi(k4.w);
  }
  e *= 0.044194173824159216f;                 // 1/sqrt(512)
  if (mask[(size_t)t * 64 + lane] == 0) e = -1e30f;

  float m = e;
  #pragma unroll
  for (int s = 1; s < 8; s <<= 1) m = fmaxf(m, __shfl_xor(m, s, 64));
  float p = __expf(e - m);
  float sum = p;
  #pragma unroll
  for (int s = 1; s < 8; s <<= 1) sum += __shfl_xor(sum, s, 64);
  P[(size_t)t * 64 + lane] = p / sum;
}

// ---------- PV: out2 rows in the (B,H,L,E)->(B,L,H*E) reshaped layout ----------
__global__ __launch_bounds__(256) void pv_kernel(
    const float* __restrict__ P,
    const unsigned short* __restrict__ Vb,
    unsigned short* __restrict__ out2) {
  const int wave = threadIdx.x >> 6, lane = threadIdx.x & 63;
  const int t = blockIdx.x * 4 + wave;
  const unsigned short* Vr = Vb + (size_t)t * 4096;
  float att = P[(size_t)t * 64 + lane];

  const int nb = t >> 11, l = t & 2047;
  const size_t tok_base = (size_t)nb * 8388608 + (size_t)(l >> 3) * 4096 +
                          (size_t)(l & 7) * 512 + lane * 8;
  #pragma unroll
  for (int hh = 0; hh < 8; ++hh) {
    float accv[8] = {0.f, 0.f, 0.f, 0.f, 0.f, 0.f, 0.f, 0.f};
    #pragma unroll
    for (int jj = 0; jj < 8; ++jj) {
      float a = __shfl(att, hh * 8 + jj, 64);
      uint4 v4 = *(const uint4*)(Vr + jj * 512 + lane * 8);
      accv[0] += a * bflo(v4.x); accv[1] += a * bfhi(v4.x);
      accv[2] += a * bflo(v4.y); accv[3] += a * bfhi(v4.y);
      accv[4] += a * bflo(v4.z); accv[5] += a * bfhi(v4.z);
      accv[6] += a * bflo(v4.w); accv[7] += a * bfhi(v4.w);
    }
    uint4 o;
    o.x = f2bf(accv[0]) | ((uint32_t)f2bf(accv[1]) << 16);
    o.y = f2bf(accv[2]) | ((uint32_t)f2bf(accv[3]) << 16);
    o.z = f2bf(accv[4]) | ((uint32_t)f2bf(accv[5]) << 16);
    o.w = f2bf(accv[6]) | ((uint32_t)f2bf(accv[7]) << 16);
    *(uint4*)(out2 + tok_base + (size_t)hh * 1048576) = o;
  }
}

// ---------- launch ----------
extern "C" void kernel_launch(void* const* d_in, const int* in_sizes, int n_in,
                              void* d_out, int out_size, void* d_ws, size_t ws_size,
                              hipStream_t stream) {
  const float* values  = (const float*)d_in[0];
  const float* keys    = (const float*)d_in[1];
  const float* queries = (const float*)d_in[2];
  const int*   mask    = (const int*)d_in[3];
  const float* Wv = (const float*)d_in[4];
  const float* bv = (const float*)d_in[5];
  const float* Wk = (const float*)d_in[6];
  const float* bk = (const float*)d_in[7];
  const float* Wq = (const float*)d_in[8];
  const float* bq = (const float*)d_in[9];
  const float* Wo = (const float*)d_in[10];
  const float* bo = (const float*)d_in[11];

  // workspace layout -- peak ~178 MB (two 67MB buffers, reused)
  unsigned short* xv  = (unsigned short*)d_ws;            // 8192*512
  unsigned short* xk  = xv + 8192 * 512;
  unsigned short* xq  = xk + 8192 * 512;
  unsigned short* Wvt = xq + 8192 * 512;                  // 4096*512 (N x K)
  unsigned short* Wkt = Wvt + 4096 * 512;
  unsigned short* Wqt = Wkt + 4096 * 512;
  unsigned short* Wot = Wqt + 4096 * 512;                 // 512*4096 (N x K)
  float*          P   = (float*)(Wot + 4096 * 512);       // 8192*64 f32
  unsigned short* bufA = (unsigned short*)(P + 8192 * 64); // 8192*4096 bf16
  unsigned short* bufB = bufA + (size_t)8192 * 4096;       // 8192*4096 bf16

  const int nx = 8192 * 512;
  cvt_f32_bf16<<<nx / 8 / 256, 256, 0, stream>>>(values, (uint32_t*)xv, nx);
  cvt_f32_bf16<<<nx / 8 / 256, 256, 0, stream>>>(keys, (uint32_t*)xk, nx);
  cvt_f32_bf16<<<nx / 8 / 256, 256, 0, stream>>>(queries, (uint32_t*)xq, nx);

  transpose_to_bf16<<<dim3(4096 / 32, 512 / 32), dim3(32, 8), 0, stream>>>(Wv, Wvt, 512, 4096);
  transpose_to_bf16<<<dim3(4096 / 32, 512 / 32), dim3(32, 8), 0, stream>>>(Wk, Wkt, 512, 4096);
  transpose_to_bf16<<<dim3(4096 / 32, 512 / 32), dim3(32, 8), 0, stream>>>(Wq, Wqt, 512, 4096);
  transpose_to_bf16<<<dim3(512 / 32, 4096 / 32), dim3(32, 8), 0, stream>>>(Wo, Wot, 4096, 512);

  // projections: M=8192, N=4096, K=512 -> Mt=32, Nt=16, KC=1, 512 blocks
  gemm8<8, false><<<512, 512, 0, stream>>>(xq, Wqt, bq, bufA, 32, 16, 1, 512);
  gemm8<8, false><<<512, 512, 0, stream>>>(xk, Wkt, bk, bufB, 32, 16, 1, 512);

  // energy + softmax -> P  (Q, K dead afterwards)
  energy_kernel<<<8192 / 4, 256, 0, stream>>>(bufA, bufB, mask, P);

  // V -> bufA (overwrites Q)
  gemm8<8, false><<<512, 512, 0, stream>>>(xv, Wvt, bv, bufA, 32, 16, 1, 512);

  // PV -> bufB (overwrites K)
  pv_kernel<<<8192 / 4, 256, 0, stream>>>(P, bufA, bufB);

  // final: out = bufB @ Wo^T + bo, split-K=8 with f32 atomics
  init_out<<<8192 * 512 / 4 / 256, 256, 0, stream>>>((float*)d_out, bo);
  gemm8<8, true><<<512, 512, 0, stream>>>(bufB, Wot, nullptr, d_out, 32, 2, 8, 4096);
}

// Round 4
// 385.795 us; speedup vs baseline: 1.9190x; 1.9190x over previous
//
#include <hip/hip_runtime.h>
#include <stdint.h>

typedef __attribute__((ext_vector_type(4))) float f32x4;
typedef __attribute__((ext_vector_type(8))) __bf16 bf16x8;

// ---------- helpers ----------
__device__ __forceinline__ unsigned short f2bf(float f) {
  union { float f; uint32_t u; } v; v.f = f;
  uint32_t u = v.u;
  return (unsigned short)((u + 0x7FFFu + ((u >> 16) & 1u)) >> 16);
}
__device__ __forceinline__ float bflo(uint32_t u) {
  union { uint32_t u; float f; } v; v.u = u << 16; return v.f;
}
__device__ __forceinline__ float bfhi(uint32_t u) {
  union { uint32_t u; float f; } v; v.u = u & 0xffff0000u; return v.f;
}

__device__ __forceinline__ void async_copy16(void* lds, const void* g) {
  __builtin_amdgcn_global_load_lds(
      (const __attribute__((address_space(1))) void*)g,
      (__attribute__((address_space(3))) void*)lds,
      16, 0, 0);
}

// ---------- f32 -> bf16 convert (flat) ----------
__global__ void cvt_f32_bf16(const float* __restrict__ in,
                             uint32_t* __restrict__ out, int n) {
  int i = blockIdx.x * blockDim.x + threadIdx.x;
  int idx = i * 8;
  if (idx >= n) return;
  float4 a = *(const float4*)(in + idx);
  float4 b = *(const float4*)(in + idx + 4);
  uint4 o;
  o.x = f2bf(a.x) | ((uint32_t)f2bf(a.y) << 16);
  o.y = f2bf(a.z) | ((uint32_t)f2bf(a.w) << 16);
  o.z = f2bf(b.x) | ((uint32_t)f2bf(b.y) << 16);
  o.w = f2bf(b.z) | ((uint32_t)f2bf(b.w) << 16);
  *(uint4*)(out + i * 4) = o;
}

// ---------- f32 (R x C) -> bf16 transposed (C x R) ----------
__global__ void transpose_to_bf16(const float* __restrict__ in,
                                  unsigned short* __restrict__ out,
                                  int R, int C) {
  __shared__ float tile[32][33];
  int c0 = blockIdx.x * 32, r0 = blockIdx.y * 32;
  int tx = threadIdx.x, ty = threadIdx.y;   // 32 x 8
  #pragma unroll
  for (int rr = 0; rr < 32; rr += 8)
    tile[ty + rr][tx] = in[(size_t)(r0 + ty + rr) * C + c0 + tx];
  __syncthreads();
  #pragma unroll
  for (int rr = 0; rr < 32; rr += 8)
    out[(size_t)(c0 + ty + rr) * R + r0 + tx] = f2bf(tile[tx][ty + rr]);
}

// ---------- 256x256 8-wave 8-phase GEMM (projections) ----------
// C(MxN) = A(MxK) @ Bt(NxK)^T + bias, bf16 out. Grid 1-D, Mt*Nt blocks (%8==0).
// LDS 128 KiB double-buffer, read-side XOR swizzle kc ^= (row&7) with
// inverse-permuted global staging source (rule #21). Bank conflicts = 0 (r3).
template <int NK>
__global__ __launch_bounds__(512, 2) void gemm8(
    const unsigned short* __restrict__ A,
    const unsigned short* __restrict__ Bt,
    const float* __restrict__ bias,
    unsigned short* __restrict__ Cout,
    int Mt, int Nt, int Kfull) {
  __shared__ unsigned short lds[2 * 2 * 256 * 64];   // 131072 B

  // bijective XCD swizzle (nwg % 8 == 0 by construction)
  const int nwg = Mt * Nt;
  const int cpx = nwg >> 3;
  const int bid = blockIdx.x;
  const int nb = (bid & 7) * cpx + (bid >> 3);
  const int bm = nb % Mt;
  const int bn = nb / Mt;
  const int N = Nt * 256;

  const int tid = threadIdx.x;
  const int wv = tid >> 6, ln = tid & 63;
  const int wm = wv >> 2, wn = wv & 3;     // 2 M-waves x 4 N-waves

  f32x4 acc[8][4] = {};

  auto stage_half = [&](int mat, int h, int t) {
    const unsigned short* src = mat ? Bt : A;
    const int rb = mat ? bn * 256 : bm * 256;
    #pragma unroll
    for (int r = 0; r < 2; ++r) {
      const int lr = h * 128 + r * 64 + wv * 8 + (ln >> 3);
      const int kcs = (ln & 7) ^ (lr & 7);           // inverse-permuted source
      const unsigned short* g =
          src + (size_t)(rb + lr) * Kfull + t * 64 + kcs * 8;
      char* dst = (char*)lds + (size_t)(t & 1) * 65536 + mat * 32768 +
                  (h * 128 + r * 64 + wv * 8) * 128;   // wave-uniform + lane*16
      async_copy16(dst, g);
    }
  };

  // prologue: K-tile 0 fully staged
  stage_half(0, 0, 0); stage_half(1, 0, 0);
  stage_half(0, 1, 0); stage_half(1, 1, 0);
  asm volatile("s_waitcnt vmcnt(0)" ::: "memory");
  __builtin_amdgcn_sched_barrier(0);
  __builtin_amdgcn_s_barrier();

  for (int t = 0; t < NK; ++t) {
    const char* buf = (const char*)lds + (size_t)(t & 1) * 65536;
    #pragma unroll
    for (int ph = 0; ph < 4; ++ph) {
      const int mh = ph >> 1, nh = ph & 1;   // C-quadrant
      bf16x8 af[4][2], bfb[2][2];
      #pragma unroll
      for (int f = 0; f < 4; ++f) {
        const int lr = wm * 128 + (mh * 4 + f) * 16 + (ln & 15);
        #pragma unroll
        for (int s = 0; s < 2; ++s) {
          const int kq = s * 4 + (ln >> 4);
          af[f][s] = *(const bf16x8*)(buf + lr * 128 + ((kq ^ (lr & 7)) * 16));
        }
      }
      #pragma unroll
      for (int gq = 0; gq < 2; ++gq) {
        const int lr = wn * 64 + (nh * 2 + gq) * 16 + (ln & 15);
        #pragma unroll
        for (int s = 0; s < 2; ++s) {
          const int kq = s * 4 + (ln >> 4);
          bfb[gq][s] =
              *(const bf16x8*)(buf + 32768 + lr * 128 + ((kq ^ (lr & 7)) * 16));
        }
      }
      if (t < NK - 1) stage_half(ph & 1, ph >> 1, t + 1);

      __builtin_amdgcn_s_barrier();
      __builtin_amdgcn_sched_barrier(0);
      __builtin_amdgcn_s_setprio(1);
      #pragma unroll
      for (int f = 0; f < 4; ++f)
        #pragma unroll
        for (int gq = 0; gq < 2; ++gq)
          #pragma unroll
          for (int s = 0; s < 2; ++s)
            // swapped operands: acc lane = M-row, reg = N-col (packed stores)
            acc[mh * 4 + f][nh * 2 + gq] = __builtin_amdgcn_mfma_f32_16x16x32_bf16(
                bfb[gq][s], af[f][s], acc[mh * 4 + f][nh * 2 + gq], 0, 0, 0);
      __builtin_amdgcn_s_setprio(0);
      __builtin_amdgcn_sched_barrier(0);
      if (ph < 3) __builtin_amdgcn_s_barrier();
    }
    asm volatile("s_waitcnt vmcnt(0)" ::: "memory");
    __builtin_amdgcn_sched_barrier(0);
    __builtin_amdgcn_s_barrier();
  }

  // epilogue: lane = M-row (ln&15), reg r = N-col (+r)
  const int m0 = bm * 256 + wm * 128 + (ln & 15);
  const int n0 = bn * 256 + wn * 64 + ((ln >> 4) << 2);
  #pragma unroll
  for (int f = 0; f < 8; ++f) {
    const int row = m0 + f * 16;
    #pragma unroll
    for (int g = 0; g < 4; ++g) {
      const int col = n0 + g * 16;
      float4 bv = *(const float4*)(bias + col);
      uint2 o;
      o.x = f2bf(acc[f][g][0] + bv.x) | ((uint32_t)f2bf(acc[f][g][1] + bv.y) << 16);
      o.y = f2bf(acc[f][g][2] + bv.z) | ((uint32_t)f2bf(acc[f][g][3] + bv.w) << 16);
      *(uint2*)(Cout + (size_t)row * N + col) = o;
    }
  }
}

// ---------- 128x128 GEMM, m97 structure (final projection, f32 out) ----------
__global__ __launch_bounds__(256) void gemm_tn_f32(
    const unsigned short* __restrict__ A,
    const unsigned short* __restrict__ Bt,
    const float* __restrict__ bias,
    float* __restrict__ Cout, int M, int N, int K) {
  constexpr int BK = 64;
  __shared__ unsigned short As[128 * BK];
  __shared__ unsigned short Bs[128 * BK];
  const int bm0 = blockIdx.x * 128;
  const int bn0 = blockIdx.y * 128;
  const int tid = threadIdx.x;
  const int wave = tid >> 6, lane = tid & 63;
  const int wm = wave >> 1, wn = wave & 1;

  f32x4 acc[4][4] = {};
  const int nk = K / BK;

  for (int kt = 0; kt < nk; ++kt) {
    const unsigned short* Ak = A + (size_t)bm0 * K + kt * BK;
    const unsigned short* Bk = Bt + (size_t)bn0 * K + kt * BK;
    #pragma unroll
    for (int i = 0; i < 4; ++i) {
      int chunk = wave * 4 + i;
      int row = chunk * 8 + (lane >> 3);
      int cole = (lane & 7) * 8;
      async_copy16((char*)As + chunk * 1024, Ak + (size_t)row * K + cole);
      async_copy16((char*)Bs + chunk * 1024, Bk + (size_t)row * K + cole);
    }
    __syncthreads();
    #pragma unroll
    for (int kk = 0; kk < 2; ++kk) {
      const int khi = kk * 32 + ((lane >> 4) & 3) * 8;
      bf16x8 af[4], bfr[4];
      #pragma unroll
      for (int a = 0; a < 4; ++a) {
        int row = wm * 64 + a * 16 + (lane & 15);
        af[a] = *(const bf16x8*)(As + row * BK + khi);
      }
      #pragma unroll
      for (int b = 0; b < 4; ++b) {
        int col = wn * 64 + b * 16 + (lane & 15);
        bfr[b] = *(const bf16x8*)(Bs + col * BK + khi);
      }
      #pragma unroll
      for (int a = 0; a < 4; ++a)
        #pragma unroll
        for (int b = 0; b < 4; ++b)
          acc[a][b] = __builtin_amdgcn_mfma_f32_16x16x32_bf16(
              af[a], bfr[b], acc[a][b], 0, 0, 0);
    }
    __syncthreads();
  }

  #pragma unroll
  for (int a = 0; a < 4; ++a) {
    int mrow = bm0 + wm * 64 + a * 16 + ((lane >> 4) & 3) * 4;
    #pragma unroll
    for (int b = 0; b < 4; ++b) {
      int ncol = bn0 + wn * 64 + b * 16 + (lane & 15);
      float bias_v = bias[ncol];
      #pragma unroll
      for (int r = 0; r < 4; ++r)
        Cout[(size_t)(mrow + r) * N + ncol] = acc[a][b][r] + bias_v;
    }
  }
}

// ---------- energy + mask + softmax -> P (f32, 8192 x 64) ----------
__global__ __launch_bounds__(256) void energy_kernel(
    const unsigned short* __restrict__ Q,
    const unsigned short* __restrict__ Kb,
    const int* __restrict__ mask,
    float* __restrict__ P) {
  const int wave = threadIdx.x >> 6, lane = threadIdx.x & 63;
  const int t = blockIdx.x * 4 + wave;
  const unsigned short* Qr = Q + (size_t)t * 4096;
  const unsigned short* Kr = Kb + (size_t)t * 4096;
  const int i = lane >> 3, j = lane & 7;

  float e = 0.f;
  #pragma unroll 4
  for (int d = 0; d < 512; d += 8) {
    uint4 q4 = *(const uint4*)(Qr + i * 512 + d);
    uint4 k4 = *(const uint4*)(Kr + j * 512 + d);
    e += bflo(q4.x) * bflo(k4.x) + bfhi(q4.x) * bfhi(k4.x);
    e += bflo(q4.y) * bflo(k4.y) + bfhi(q4.y) * bfhi(k4.y);
    e += bflo(q4.z) * bflo(k4.z) + bfhi(q4.z) * bfhi(k4.z);
    e += bflo(q4.w) * bflo(k4.w) + bfhi(q4.w) * bfhi(k4.w);
  }
  e *= 0.044194173824159216f;                 // 1/sqrt(512)
  if (mask[(size_t)t * 64 + lane] == 0) e = -1e30f;

  float m = e;
  #pragma unroll
  for (int s = 1; s < 8; s <<= 1) m = fmaxf(m, __shfl_xor(m, s, 64));
  float p = __expf(e - m);
  float sum = p;
  #pragma unroll
  for (int s = 1; s < 8; s <<= 1) sum += __shfl_xor(sum, s, 64);
  P[(size_t)t * 64 + lane] = p / sum;
}

// ---------- PV: out2 rows in the (B,H,L,E)->(B,L,H*E) reshaped layout ----------
__global__ __launch_bounds__(256) void pv_kernel(
    const float* __restrict__ P,
    const unsigned short* __restrict__ Vb,
    unsigned short* __restrict__ out2) {
  const int wave = threadIdx.x >> 6, lane = threadIdx.x & 63;
  const int t = blockIdx.x * 4 + wave;
  const unsigned short* Vr = Vb + (size_t)t * 4096;
  float att = P[(size_t)t * 64 + lane];

  const int nb = t >> 11, l = t & 2047;
  const size_t tok_base = (size_t)nb * 8388608 + (size_t)(l >> 3) * 4096 +
                          (size_t)(l & 7) * 512 + lane * 8;
  #pragma unroll
  for (int hh = 0; hh < 8; ++hh) {
    float accv[8] = {0.f, 0.f, 0.f, 0.f, 0.f, 0.f, 0.f, 0.f};
    #pragma unroll
    for (int jj = 0; jj < 8; ++jj) {
      float a = __shfl(att, hh * 8 + jj, 64);
      uint4 v4 = *(const uint4*)(Vr + jj * 512 + lane * 8);
      accv[0] += a * bflo(v4.x); accv[1] += a * bfhi(v4.x);
      accv[2] += a * bflo(v4.y); accv[3] += a * bfhi(v4.y);
      accv[4] += a * bflo(v4.z); accv[5] += a * bfhi(v4.z);
      accv[6] += a * bflo(v4.w); accv[7] += a * bfhi(v4.w);
    }
    uint4 o;
    o.x = f2bf(accv[0]) | ((uint32_t)f2bf(accv[1]) << 16);
    o.y = f2bf(accv[2]) | ((uint32_t)f2bf(accv[3]) << 16);
    o.z = f2bf(accv[4]) | ((uint32_t)f2bf(accv[5]) << 16);
    o.w = f2bf(accv[6]) | ((uint32_t)f2bf(accv[7]) << 16);
    *(uint4*)(out2 + tok_base + (size_t)hh * 1048576) = o;
  }
}

// ---------- launch ----------
extern "C" void kernel_launch(void* const* d_in, const int* in_sizes, int n_in,
                              void* d_out, int out_size, void* d_ws, size_t ws_size,
                              hipStream_t stream) {
  const float* values  = (const float*)d_in[0];
  const float* keys    = (const float*)d_in[1];
  const float* queries = (const float*)d_in[2];
  const int*   mask    = (const int*)d_in[3];
  const float* Wv = (const float*)d_in[4];
  const float* bv = (const float*)d_in[5];
  const float* Wk = (const float*)d_in[6];
  const float* bk = (const float*)d_in[7];
  const float* Wq = (const float*)d_in[8];
  const float* bq = (const float*)d_in[9];
  const float* Wo = (const float*)d_in[10];
  const float* bo = (const float*)d_in[11];

  // workspace layout -- peak ~178 MB (two 67MB buffers, reused)
  unsigned short* xv  = (unsigned short*)d_ws;            // 8192*512
  unsigned short* xk  = xv + 8192 * 512;
  unsigned short* xq  = xk + 8192 * 512;
  unsigned short* Wvt = xq + 8192 * 512;                  // 4096*512 (N x K)
  unsigned short* Wkt = Wvt + 4096 * 512;
  unsigned short* Wqt = Wkt + 4096 * 512;
  unsigned short* Wot = Wqt + 4096 * 512;                 // 512*4096 (N x K)
  float*          P   = (float*)(Wot + 4096 * 512);       // 8192*64 f32
  unsigned short* bufA = (unsigned short*)(P + 8192 * 64); // 8192*4096 bf16
  unsigned short* bufB = bufA + (size_t)8192 * 4096;       // 8192*4096 bf16

  const int nx = 8192 * 512;
  cvt_f32_bf16<<<nx / 8 / 256, 256, 0, stream>>>(values, (uint32_t*)xv, nx);
  cvt_f32_bf16<<<nx / 8 / 256, 256, 0, stream>>>(keys, (uint32_t*)xk, nx);
  cvt_f32_bf16<<<nx / 8 / 256, 256, 0, stream>>>(queries, (uint32_t*)xq, nx);

  transpose_to_bf16<<<dim3(4096 / 32, 512 / 32), dim3(32, 8), 0, stream>>>(Wv, Wvt, 512, 4096);
  transpose_to_bf16<<<dim3(4096 / 32, 512 / 32), dim3(32, 8), 0, stream>>>(Wk, Wkt, 512, 4096);
  transpose_to_bf16<<<dim3(4096 / 32, 512 / 32), dim3(32, 8), 0, stream>>>(Wq, Wqt, 512, 4096);
  transpose_to_bf16<<<dim3(512 / 32, 4096 / 32), dim3(32, 8), 0, stream>>>(Wo, Wot, 4096, 512);

  // projections: M=8192, N=4096, K=512 -> Mt=32, Nt=16, 512 blocks
  gemm8<8><<<512, 512, 0, stream>>>(xq, Wqt, bq, bufA, 32, 16, 512);
  gemm8<8><<<512, 512, 0, stream>>>(xk, Wkt, bk, bufB, 32, 16, 512);

  // energy + softmax -> P  (Q, K dead afterwards)
  energy_kernel<<<8192 / 4, 256, 0, stream>>>(bufA, bufB, mask, P);

  // V -> bufA (overwrites Q)
  gemm8<8><<<512, 512, 0, stream>>>(xv, Wvt, bv, bufA, 32, 16, 512);

  // PV -> bufB (overwrites K)
  pv_kernel<<<8192 / 4, 256, 0, stream>>>(P, bufA, bufB);

  // final: out = bufB @ Wo^T + bo (direct f32 stores, proven r2 path)
  gemm_tn_f32<<<dim3(8192 / 128, 512 / 128), 256, 0, stream>>>(
      bufB, Wot, bo, (float*)d_out, 8192, 512, 4096);
}

// Round 5
// 345.818 us; speedup vs baseline: 2.1409x; 1.1156x over previous
//
#include <hip/hip_runtime.h>
#include <stdint.h>

typedef __attribute__((ext_vector_type(4))) float f32x4;
typedef __attribute__((ext_vector_type(8))) __bf16 bf16x8;

// ---------- helpers ----------
__device__ __forceinline__ unsigned short f2bf(float f) {
  union { float f; uint32_t u; } v; v.f = f;
  uint32_t u = v.u;
  return (unsigned short)((u + 0x7FFFu + ((u >> 16) & 1u)) >> 16);
}
__device__ __forceinline__ float bflo(uint32_t u) {
  union { uint32_t u; float f; } v; v.u = u << 16; return v.f;
}
__device__ __forceinline__ float bfhi(uint32_t u) {
  union { uint32_t u; float f; } v; v.u = u & 0xffff0000u; return v.f;
}

__device__ __forceinline__ void async_copy16(void* lds, const void* g) {
  __builtin_amdgcn_global_load_lds(
      (const __attribute__((address_space(1))) void*)g,
      (__attribute__((address_space(3))) void*)lds,
      16, 0, 0);
}

// ---------- f32 -> bf16 convert (flat) ----------
__global__ void cvt_f32_bf16(const float* __restrict__ in,
                             uint32_t* __restrict__ out, int n) {
  int i = blockIdx.x * blockDim.x + threadIdx.x;
  int idx = i * 8;
  if (idx >= n) return;
  float4 a = *(const float4*)(in + idx);
  float4 b = *(const float4*)(in + idx + 4);
  uint4 o;
  o.x = f2bf(a.x) | ((uint32_t)f2bf(a.y) << 16);
  o.y = f2bf(a.z) | ((uint32_t)f2bf(a.w) << 16);
  o.z = f2bf(b.x) | ((uint32_t)f2bf(b.y) << 16);
  o.w = f2bf(b.z) | ((uint32_t)f2bf(b.w) << 16);
  *(uint4*)(out + i * 4) = o;
}

// ---------- f32 (R x C) -> bf16 transposed (C x R) ----------
__global__ void transpose_to_bf16(const float* __restrict__ in,
                                  unsigned short* __restrict__ out,
                                  int R, int C) {
  __shared__ float tile[32][33];
  int c0 = blockIdx.x * 32, r0 = blockIdx.y * 32;
  int tx = threadIdx.x, ty = threadIdx.y;   // 32 x 8
  #pragma unroll
  for (int rr = 0; rr < 32; rr += 8)
    tile[ty + rr][tx] = in[(size_t)(r0 + ty + rr) * C + c0 + tx];
  __syncthreads();
  #pragma unroll
  for (int rr = 0; rr < 32; rr += 8)
    out[(size_t)(c0 + ty + rr) * R + r0 + tx] = f2bf(tile[tx][ty + rr]);
}

// ---------- 256x256 8-wave GEMM, counted-vmcnt 4-phase/K-tile schedule ----------
// C(MxN) = A(MxK) @ Bt(NxK)^T (+bias, bf16 out) or f32 partials per K-chunk.
// Gray-code quadrants (0,0)->(0,1)->(1,1)->(1,0) with fragment reuse.
// Half-tiles: h0=A-half0, h1=B-half1, h2=A-half1, h3=B-half0 (stage order).
// Stage schedule in tile t: p0->(t+1).h3, p1->(t+2).h0, p2->(t+2).h1, p3->(t+2).h2.
// Boundary wait vmcnt(6) = 3 half-tiles in flight (T4); tails 0 / none.
template <int NK, bool PARTIAL>
__global__ __launch_bounds__(512, 2) void gemm256(
    const unsigned short* __restrict__ A,
    const unsigned short* __restrict__ Bt,
    const float* __restrict__ bias,
    void* __restrict__ Cout,
    int Mt, int Nt, int KC, int Kfull) {
  static_assert(NK >= 3, "schedule needs >=3 K-tiles");
  __shared__ unsigned short lds[2 * 2 * 256 * 64];   // 131072 B

  const int nwg = Mt * Nt * KC;
  const int cpx = nwg >> 3;
  const int bid = blockIdx.x;
  const int nb = (bid & 7) * cpx + (bid >> 3);       // bijective XCD swizzle
  const int bm = nb % Mt;
  const int rest = nb / Mt;
  const int bn = rest % Nt;
  const int kc = rest / Nt;
  const int N = Nt * 256;
  const size_t koff = (size_t)kc * (NK * 64);

  const int tid = threadIdx.x;
  const int wv = tid >> 6, ln = tid & 63;
  const int wm = wv >> 2, wn = wv & 3;     // 2 M-waves x 4 N-waves

  f32x4 acc[8][4] = {};
  bf16x8 af[4][2];
  bf16x8 bfb[2][2];

  // stage A-half h of K-tile tt: rows {r*128 + h*64 + [0..63]} (2 loads/thread)
  auto stage_A = [&](int h, int tt) {
    #pragma unroll
    for (int r = 0; r < 2; ++r) {
      const int rb = r * 128 + h * 64 + wv * 8;      // 8-row block, wave-uniform
      const int row = rb + (ln >> 3);
      const int kcs = (ln & 7) ^ (row & 7);          // inverse-permuted source
      const unsigned short* g =
          A + (size_t)(bm * 256 + row) * Kfull + koff + tt * 64 + kcs * 8;
      char* dst = (char*)lds + (size_t)(tt & 1) * 65536 + rb * 128;
      async_copy16(dst, g);
    }
  };
  // stage B-half h: rows {s*64 + h*32 + [0..31]} for strips s=0..3
  auto stage_B = [&](int h, int tt) {
    #pragma unroll
    for (int r = 0; r < 2; ++r) {
      const int s = r * 2 + (wv >> 2);
      const int rb = s * 64 + h * 32 + (wv & 3) * 8;
      const int row = rb + (ln >> 3);
      const int kcs = (ln & 7) ^ (row & 7);
      const unsigned short* g =
          Bt + (size_t)(bn * 256 + row) * Kfull + koff + tt * 64 + kcs * 8;
      char* dst = (char*)lds + (size_t)(tt & 1) * 65536 + 32768 + rb * 128;
      async_copy16(dst, g);
    }
  };
  auto load_af = [&](int mh, const char* buf) {
    #pragma unroll
    for (int f = 0; f < 4; ++f) {
      const int lr = wm * 128 + (mh * 4 + f) * 16 + (ln & 15);
      #pragma unroll
      for (int s = 0; s < 2; ++s) {
        const int kq = s * 4 + (ln >> 4);
        af[f][s] = *(const bf16x8*)(buf + lr * 128 + ((kq ^ (lr & 7)) * 16));
      }
    }
  };
  auto load_bf = [&](int nh, const char* buf) {
    #pragma unroll
    for (int gq = 0; gq < 2; ++gq) {
      const int lr = wn * 64 + (nh * 2 + gq) * 16 + (ln & 15);
      #pragma unroll
      for (int s = 0; s < 2; ++s) {
        const int kq = s * 4 + (ln >> 4);
        bfb[gq][s] =
            *(const bf16x8*)(buf + 32768 + lr * 128 + ((kq ^ (lr & 7)) * 16));
      }
    }
  };
  auto mfma_quad = [&](int mh, int nh) {
    __builtin_amdgcn_sched_barrier(0);
    __builtin_amdgcn_s_barrier();          // pre-MFMA: all loads+stages issued
    __builtin_amdgcn_sched_barrier(0);
    __builtin_amdgcn_s_setprio(1);
    #pragma unroll
    for (int f = 0; f < 4; ++f)
      #pragma unroll
      for (int gq = 0; gq < 2; ++gq)
        #pragma unroll
        for (int s = 0; s < 2; ++s)
          acc[mh * 4 + f][nh * 2 + gq] = __builtin_amdgcn_mfma_f32_16x16x32_bf16(
              bfb[gq][s], af[f][s], acc[mh * 4 + f][nh * 2 + gq], 0, 0, 0);
    __builtin_amdgcn_s_setprio(0);
    __builtin_amdgcn_sched_barrier(0);
  };

  // prologue: tile0 halves h0..h3, tile1 halves h0..h2 (7 halves, 14 loads)
  stage_A(0, 0); stage_B(1, 0); stage_A(1, 0); stage_B(0, 0);
  stage_A(0, 1); stage_B(1, 1); stage_A(1, 1);
  asm volatile("s_waitcnt vmcnt(6)" ::: "memory");   // force tile0 complete
  __builtin_amdgcn_sched_barrier(0);
  __builtin_amdgcn_s_barrier();

  for (int t = 0; t < NK; ++t) {
    const char* buf = (const char*)lds + (size_t)(t & 1) * 65536;
    // p0 = (0,0): fresh A0+B0; stage (t+1).h3 = B0
    load_af(0, buf); load_bf(0, buf);
    if (t + 1 < NK) stage_B(0, t + 1);
    mfma_quad(0, 0);
    __builtin_amdgcn_s_barrier();
    // p1 = (0,1): fresh B1 (af reused); stage (t+2).h0 = A0
    load_bf(1, buf);
    if (t + 2 < NK) stage_A(0, t + 2);
    mfma_quad(0, 1);
    __builtin_amdgcn_s_barrier();
    // p2 = (1,1): fresh A1 (bfb reused); stage (t+2).h1 = B1
    load_af(1, buf);
    if (t + 2 < NK) stage_B(1, t + 2);
    mfma_quad(1, 1);
    __builtin_amdgcn_s_barrier();
    // p3 = (1,0): re-read B0 (af reused); stage (t+2).h2 = A1
    load_bf(0, buf);
    if (t + 2 < NK) stage_A(1, t + 2);
    mfma_quad(1, 0);
    // boundary: counted wait -- forces tile t+1 complete, leaves 3 halves in flight
    if (t + 2 < NK) {
      asm volatile("s_waitcnt vmcnt(6)" ::: "memory");
    } else if (t + 1 < NK) {
      asm volatile("s_waitcnt vmcnt(0)" ::: "memory");
    }
    __builtin_amdgcn_sched_barrier(0);
    __builtin_amdgcn_s_barrier();
  }

  // epilogue: swapped-operand layout -- lane = M-row (ln&15), reg r = N-col
  const int m0 = bm * 256 + wm * 128 + (ln & 15);
  const int n0 = bn * 256 + wn * 64 + ((ln >> 4) << 2);
  if (PARTIAL) {
    float* Cp = (float*)Cout + (size_t)kc * ((size_t)Mt * 256) * N;
    #pragma unroll
    for (int f = 0; f < 8; ++f) {
      const int row = m0 + f * 16;
      #pragma unroll
      for (int g = 0; g < 4; ++g)
        *(f32x4*)(Cp + (size_t)row * N + n0 + g * 16) = acc[f][g];
    }
  } else {
    unsigned short* C = (unsigned short*)Cout;
    #pragma unroll
    for (int f = 0; f < 8; ++f) {
      const int row = m0 + f * 16;
      #pragma unroll
      for (int g = 0; g < 4; ++g) {
        const int col = n0 + g * 16;
        float4 bv = *(const float4*)(bias + col);
        uint2 o;
        o.x = f2bf(acc[f][g][0] + bv.x) | ((uint32_t)f2bf(acc[f][g][1] + bv.y) << 16);
        o.y = f2bf(acc[f][g][2] + bv.z) | ((uint32_t)f2bf(acc[f][g][3] + bv.w) << 16);
        *(uint2*)(C + (size_t)row * N + col) = o;
      }
    }
  }
}

// ---------- reduce 4 f32 partials + bias -> out ----------
__global__ void reduce4_bias(const float* __restrict__ p,
                             const float* __restrict__ bo,
                             float* __restrict__ out) {
  const size_t S = (size_t)8192 * 512;
  size_t i = ((size_t)blockIdx.x * 256 + threadIdx.x) * 4;
  float4 a = *(const float4*)(p + i);
  float4 b = *(const float4*)(p + S + i);
  float4 c = *(const float4*)(p + 2 * S + i);
  float4 d = *(const float4*)(p + 3 * S + i);
  float4 bb = *(const float4*)(bo + (int)(i & 511));
  float4 o;
  o.x = a.x + b.x + c.x + d.x + bb.x;
  o.y = a.y + b.y + c.y + d.y + bb.y;
  o.z = a.z + b.z + c.z + d.z + bb.z;
  o.w = a.w + b.w + c.w + d.w + bb.w;
  *(float4*)(out + i) = o;
}

// ---------- energy + mask + softmax -> P (f32, 8192 x 64) ----------
__global__ __launch_bounds__(256) void energy_kernel(
    const unsigned short* __restrict__ Q,
    const unsigned short* __restrict__ Kb,
    const int* __restrict__ mask,
    float* __restrict__ P) {
  const int wave = threadIdx.x >> 6, lane = threadIdx.x & 63;
  const int t = blockIdx.x * 4 + wave;
  const unsigned short* Qr = Q + (size_t)t * 4096;
  const unsigned short* Kr = Kb + (size_t)t * 4096;
  const int i = lane >> 3, j = lane & 7;

  float e = 0.f;
  #pragma unroll 4
  for (int d = 0; d < 512; d += 8) {
    uint4 q4 = *(const uint4*)(Qr + i * 512 + d);
    uint4 k4 = *(const uint4*)(Kr + j * 512 + d);
    e += bflo(q4.x) * bflo(k4.x) + bfhi(q4.x) * bfhi(k4.x);
    e += bflo(q4.y) * bflo(k4.y) + bfhi(q4.y) * bfhi(k4.y);
    e += bflo(q4.z) * bflo(k4.z) + bfhi(q4.z) * bfhi(k4.z);
    e += bflo(q4.w) * bflo(k4.w) + bfhi(q4.w) * bfhi(k4.w);
  }
  e *= 0.044194173824159216f;                 // 1/sqrt(512)
  if (mask[(size_t)t * 64 + lane] == 0) e = -1e30f;

  float m = e;
  #pragma unroll
  for (int s = 1; s < 8; s <<= 1) m = fmaxf(m, __shfl_xor(m, s, 64));
  float p = __expf(e - m);
  float sum = p;
  #pragma unroll
  for (int s = 1; s < 8; s <<= 1) sum += __shfl_xor(sum, s, 64);
  P[(size_t)t * 64 + lane] = p / sum;
}

// ---------- PV: out2 rows in the (B,H,L,E)->(B,L,H*E) reshaped layout ----------
__global__ __launch_bounds__(256) void pv_kernel(
    const float* __restrict__ P,
    const unsigned short* __restrict__ Vb,
    unsigned short* __restrict__ out2) {
  const int wave = threadIdx.x >> 6, lane = threadIdx.x & 63;
  const int t = blockIdx.x * 4 + wave;
  const unsigned short* Vr = Vb + (size_t)t * 4096;
  float att = P[(size_t)t * 64 + lane];

  const int nb = t >> 11, l = t & 2047;
  const size_t tok_base = (size_t)nb * 8388608 + (size_t)(l >> 3) * 4096 +
                          (size_t)(l & 7) * 512 + lane * 8;
  #pragma unroll
  for (int hh = 0; hh < 8; ++hh) {
    float accv[8] = {0.f, 0.f, 0.f, 0.f, 0.f, 0.f, 0.f, 0.f};
    #pragma unroll
    for (int jj = 0; jj < 8; ++jj) {
      float a = __shfl(att, hh * 8 + jj, 64);
      uint4 v4 = *(const uint4*)(Vr + jj * 512 + lane * 8);
      accv[0] += a * bflo(v4.x); accv[1] += a * bfhi(v4.x);
      accv[2] += a * bflo(v4.y); accv[3] += a * bfhi(v4.y);
      accv[4] += a * bflo(v4.z); accv[5] += a * bfhi(v4.z);
      accv[6] += a * bflo(v4.w); accv[7] += a * bfhi(v4.w);
    }
    uint4 o;
    o.x = f2bf(accv[0]) | ((uint32_t)f2bf(accv[1]) << 16);
    o.y = f2bf(accv[2]) | ((uint32_t)f2bf(accv[3]) << 16);
    o.z = f2bf(accv[4]) | ((uint32_t)f2bf(accv[5]) << 16);
    o.w = f2bf(accv[6]) | ((uint32_t)f2bf(accv[7]) << 16);
    *(uint4*)(out2 + tok_base + (size_t)hh * 1048576) = o;
  }
}

// ---------- launch ----------
extern "C" void kernel_launch(void* const* d_in, const int* in_sizes, int n_in,
                              void* d_out, int out_size, void* d_ws, size_t ws_size,
                              hipStream_t stream) {
  const float* values  = (const float*)d_in[0];
  const float* keys    = (const float*)d_in[1];
  const float* queries = (const float*)d_in[2];
  const int*   mask    = (const int*)d_in[3];
  const float* Wv = (const float*)d_in[4];
  const float* bv = (const float*)d_in[5];
  const float* Wk = (const float*)d_in[6];
  const float* bk = (const float*)d_in[7];
  const float* Wq = (const float*)d_in[8];
  const float* bq = (const float*)d_in[9];
  const float* Wo = (const float*)d_in[10];
  const float* bo = (const float*)d_in[11];

  // workspace layout -- peak ~178 MB (two 67MB buffers, reused)
  unsigned short* xv  = (unsigned short*)d_ws;            // 8192*512
  unsigned short* xk  = xv + 8192 * 512;
  unsigned short* xq  = xk + 8192 * 512;
  unsigned short* Wvt = xq + 8192 * 512;                  // 4096*512 (N x K)
  unsigned short* Wkt = Wvt + 4096 * 512;
  unsigned short* Wqt = Wkt + 4096 * 512;
  unsigned short* Wot = Wqt + 4096 * 512;                 // 512*4096 (N x K)
  float*          P   = (float*)(Wot + 4096 * 512);       // 8192*64 f32
  unsigned short* bufA = (unsigned short*)(P + 8192 * 64); // 8192*4096 bf16
  unsigned short* bufB = bufA + (size_t)8192 * 4096;       // 8192*4096 bf16

  const int nx = 8192 * 512;
  cvt_f32_bf16<<<nx / 8 / 256, 256, 0, stream>>>(values, (uint32_t*)xv, nx);
  cvt_f32_bf16<<<nx / 8 / 256, 256, 0, stream>>>(keys, (uint32_t*)xk, nx);
  cvt_f32_bf16<<<nx / 8 / 256, 256, 0, stream>>>(queries, (uint32_t*)xq, nx);

  transpose_to_bf16<<<dim3(4096 / 32, 512 / 32), dim3(32, 8), 0, stream>>>(Wv, Wvt, 512, 4096);
  transpose_to_bf16<<<dim3(4096 / 32, 512 / 32), dim3(32, 8), 0, stream>>>(Wk, Wkt, 512, 4096);
  transpose_to_bf16<<<dim3(4096 / 32, 512 / 32), dim3(32, 8), 0, stream>>>(Wq, Wqt, 512, 4096);
  transpose_to_bf16<<<dim3(512 / 32, 4096 / 32), dim3(32, 8), 0, stream>>>(Wo, Wot, 4096, 512);

  // projections: M=8192, N=4096, K=512 -> Mt=32, Nt=16, KC=1, 512 blocks
  gemm256<8, false><<<512, 512, 0, stream>>>(xq, Wqt, bq, bufA, 32, 16, 1, 512);
  gemm256<8, false><<<512, 512, 0, stream>>>(xk, Wkt, bk, bufB, 32, 16, 1, 512);

  // energy + softmax -> P  (Q, K dead afterwards)
  energy_kernel<<<8192 / 4, 256, 0, stream>>>(bufA, bufB, mask, P);

  // V -> bufA (overwrites Q)
  gemm256<8, false><<<512, 512, 0, stream>>>(xv, Wvt, bv, bufA, 32, 16, 1, 512);

  // PV -> bufB (overwrites K)
  pv_kernel<<<8192 / 4, 256, 0, stream>>>(P, bufA, bufB);

  // final: split-K=4 f32 partials into bufA (exactly 67MB), then reduce+bias
  gemm256<16, true><<<256, 512, 0, stream>>>(bufB, Wot, nullptr, (float*)bufA,
                                             32, 2, 4, 4096);
  reduce4_bias<<<4096, 256, 0, stream>>>((float*)bufA, bo, (float*)d_out);
}

// Round 7
// 276.496 us; speedup vs baseline: 2.6776x; 1.2507x over previous
//
#include <hip/hip_runtime.h>
#include <stdint.h>

typedef __attribute__((ext_vector_type(4))) float f32x4;
typedef __attribute__((ext_vector_type(8))) __bf16 bf16x8;

// ---------- helpers ----------
__device__ __forceinline__ unsigned short f2bf(float f) {
  union { float f; uint32_t u; } v; v.f = f;
  uint32_t u = v.u;
  return (unsigned short)((u + 0x7FFFu + ((u >> 16) & 1u)) >> 16);
}
__device__ __forceinline__ float bflo(uint32_t u) {
  union { uint32_t u; float f; } v; v.u = u << 16; return v.f;
}
__device__ __forceinline__ float bfhi(uint32_t u) {
  union { uint32_t u; float f; } v; v.u = u & 0xffff0000u; return v.f;
}

__device__ __forceinline__ void async_copy16(void* lds, const void* g) {
  __builtin_amdgcn_global_load_lds(
      (const __attribute__((address_space(1))) void*)g,
      (__attribute__((address_space(3))) void*)lds,
      16, 0, 0);
}

// ---------- f32 -> bf16 convert: 3 tensors in one launch (blockIdx.y picks) ----------
__global__ void cvt3_f32_bf16(const float* __restrict__ in0,
                              const float* __restrict__ in1,
                              const float* __restrict__ in2,
                              uint32_t* __restrict__ out, int n) {
  const float* in = (blockIdx.y == 0) ? in0 : (blockIdx.y == 1) ? in1 : in2;
  // each tensor = n bf16 = n/2 uint32 words (was n/4: the round-6 bug)
  uint32_t* o = out + (size_t)blockIdx.y * (n / 2);
  int i = blockIdx.x * blockDim.x + threadIdx.x;
  int idx = i * 8;
  if (idx >= n) return;
  float4 a = *(const float4*)(in + idx);
  float4 b = *(const float4*)(in + idx + 4);
  uint4 ov;
  ov.x = f2bf(a.x) | ((uint32_t)f2bf(a.y) << 16);
  ov.y = f2bf(a.z) | ((uint32_t)f2bf(a.w) << 16);
  ov.z = f2bf(b.x) | ((uint32_t)f2bf(b.y) << 16);
  ov.w = f2bf(b.z) | ((uint32_t)f2bf(b.w) << 16);
  *(uint4*)(o + i * 4) = ov;
}

// ---------- f32 (R x C) -> bf16 transposed (C x R); gridDim.z picks tensor ----------
__global__ void transpose3_to_bf16(const float* __restrict__ in0,
                                   const float* __restrict__ in1,
                                   const float* __restrict__ in2,
                                   unsigned short* __restrict__ out,
                                   int R, int C) {
  const float* in = (blockIdx.z == 0) ? in0 : (blockIdx.z == 1) ? in1 : in2;
  unsigned short* o = out + (size_t)blockIdx.z * ((size_t)R * C);
  __shared__ float tile[32][33];
  int c0 = blockIdx.x * 32, r0 = blockIdx.y * 32;
  int tx = threadIdx.x, ty = threadIdx.y;   // 32 x 8
  #pragma unroll
  for (int rr = 0; rr < 32; rr += 8)
    tile[ty + rr][tx] = in[(size_t)(r0 + ty + rr) * C + c0 + tx];
  __syncthreads();
  #pragma unroll
  for (int rr = 0; rr < 32; rr += 8)
    o[(size_t)(c0 + ty + rr) * R + r0 + tx] = f2bf(tile[tx][ty + rr]);
}

__global__ void transpose_to_bf16(const float* __restrict__ in,
                                  unsigned short* __restrict__ out,
                                  int R, int C) {
  __shared__ float tile[32][33];
  int c0 = blockIdx.x * 32, r0 = blockIdx.y * 32;
  int tx = threadIdx.x, ty = threadIdx.y;
  #pragma unroll
  for (int rr = 0; rr < 32; rr += 8)
    tile[ty + rr][tx] = in[(size_t)(r0 + ty + rr) * C + c0 + tx];
  __syncthreads();
  #pragma unroll
  for (int rr = 0; rr < 32; rr += 8)
    out[(size_t)(c0 + ty + rr) * R + r0 + tx] = f2bf(tile[tx][ty + rr]);
}

// ---------- 256x256 8-wave GEMM, counted-vmcnt 4-phase/K-tile schedule ----------
template <int NK, bool PARTIAL>
__global__ __launch_bounds__(512, 2) void gemm256(
    const unsigned short* __restrict__ A,
    const unsigned short* __restrict__ Bt,
    const float* __restrict__ bias,
    void* __restrict__ Cout,
    int Mt, int Nt, int KC, int Kfull) {
  static_assert(NK >= 3, "schedule needs >=3 K-tiles");
  __shared__ unsigned short lds[2 * 2 * 256 * 64];   // 131072 B

  const int nwg = Mt * Nt * KC;
  const int cpx = nwg >> 3;
  const int bid = blockIdx.x;
  const int nb = (bid & 7) * cpx + (bid >> 3);       // bijective XCD swizzle
  const int bm = nb % Mt;
  const int rest = nb / Mt;
  const int bn = rest % Nt;
  const int kc = rest / Nt;
  const int N = Nt * 256;
  const size_t koff = (size_t)kc * (NK * 64);

  const int tid = threadIdx.x;
  const int wv = tid >> 6, ln = tid & 63;
  const int wm = wv >> 2, wn = wv & 3;     // 2 M-waves x 4 N-waves

  f32x4 acc[8][4] = {};
  bf16x8 af[4][2];
  bf16x8 bfb[2][2];

  auto stage_A = [&](int h, int tt) {
    #pragma unroll
    for (int r = 0; r < 2; ++r) {
      const int rb = r * 128 + h * 64 + wv * 8;
      const int row = rb + (ln >> 3);
      const int kcs = (ln & 7) ^ (row & 7);
      const unsigned short* g =
          A + (size_t)(bm * 256 + row) * Kfull + koff + tt * 64 + kcs * 8;
      char* dst = (char*)lds + (size_t)(tt & 1) * 65536 + rb * 128;
      async_copy16(dst, g);
    }
  };
  auto stage_B = [&](int h, int tt) {
    #pragma unroll
    for (int r = 0; r < 2; ++r) {
      const int s = r * 2 + (wv >> 2);
      const int rb = s * 64 + h * 32 + (wv & 3) * 8;
      const int row = rb + (ln >> 3);
      const int kcs = (ln & 7) ^ (row & 7);
      const unsigned short* g =
          Bt + (size_t)(bn * 256 + row) * Kfull + koff + tt * 64 + kcs * 8;
      char* dst = (char*)lds + (size_t)(tt & 1) * 65536 + 32768 + rb * 128;
      async_copy16(dst, g);
    }
  };
  auto load_af = [&](int mh, const char* buf) {
    #pragma unroll
    for (int f = 0; f < 4; ++f) {
      const int lr = wm * 128 + (mh * 4 + f) * 16 + (ln & 15);
      #pragma unroll
      for (int s = 0; s < 2; ++s) {
        const int kq = s * 4 + (ln >> 4);
        af[f][s] = *(const bf16x8*)(buf + lr * 128 + ((kq ^ (lr & 7)) * 16));
      }
    }
  };
  auto load_bf = [&](int nh, const char* buf) {
    #pragma unroll
    for (int gq = 0; gq < 2; ++gq) {
      const int lr = wn * 64 + (nh * 2 + gq) * 16 + (ln & 15);
      #pragma unroll
      for (int s = 0; s < 2; ++s) {
        const int kq = s * 4 + (ln >> 4);
        bfb[gq][s] =
            *(const bf16x8*)(buf + 32768 + lr * 128 + ((kq ^ (lr & 7)) * 16));
      }
    }
  };
  auto mfma_quad = [&](int mh, int nh) {
    __builtin_amdgcn_sched_barrier(0);
    __builtin_amdgcn_s_barrier();
    __builtin_amdgcn_sched_barrier(0);
    __builtin_amdgcn_s_setprio(1);
    #pragma unroll
    for (int f = 0; f < 4; ++f)
      #pragma unroll
      for (int gq = 0; gq < 2; ++gq)
        #pragma unroll
        for (int s = 0; s < 2; ++s)
          acc[mh * 4 + f][nh * 2 + gq] = __builtin_amdgcn_mfma_f32_16x16x32_bf16(
              bfb[gq][s], af[f][s], acc[mh * 4 + f][nh * 2 + gq], 0, 0, 0);
    __builtin_amdgcn_s_setprio(0);
    __builtin_amdgcn_sched_barrier(0);
  };

  stage_A(0, 0); stage_B(1, 0); stage_A(1, 0); stage_B(0, 0);
  stage_A(0, 1); stage_B(1, 1); stage_A(1, 1);
  asm volatile("s_waitcnt vmcnt(6)" ::: "memory");
  __builtin_amdgcn_sched_barrier(0);
  __builtin_amdgcn_s_barrier();

  for (int t = 0; t < NK; ++t) {
    const char* buf = (const char*)lds + (size_t)(t & 1) * 65536;
    load_af(0, buf); load_bf(0, buf);
    if (t + 1 < NK) stage_B(0, t + 1);
    mfma_quad(0, 0);
    __builtin_amdgcn_s_barrier();
    load_bf(1, buf);
    if (t + 2 < NK) stage_A(0, t + 2);
    mfma_quad(0, 1);
    __builtin_amdgcn_s_barrier();
    load_af(1, buf);
    if (t + 2 < NK) stage_B(1, t + 2);
    mfma_quad(1, 1);
    __builtin_amdgcn_s_barrier();
    load_bf(0, buf);
    if (t + 2 < NK) stage_A(1, t + 2);
    mfma_quad(1, 0);
    if (t + 2 < NK) {
      asm volatile("s_waitcnt vmcnt(6)" ::: "memory");
    } else if (t + 1 < NK) {
      asm volatile("s_waitcnt vmcnt(0)" ::: "memory");
    }
    __builtin_amdgcn_sched_barrier(0);
    __builtin_amdgcn_s_barrier();
  }

  const int m0 = bm * 256 + wm * 128 + (ln & 15);
  const int n0 = bn * 256 + wn * 64 + ((ln >> 4) << 2);
  if (PARTIAL) {
    float* Cp = (float*)Cout + (size_t)kc * ((size_t)Mt * 256) * N;
    #pragma unroll
    for (int f = 0; f < 8; ++f) {
      const int row = m0 + f * 16;
      #pragma unroll
      for (int g = 0; g < 4; ++g)
        *(f32x4*)(Cp + (size_t)row * N + n0 + g * 16) = acc[f][g];
    }
  } else {
    unsigned short* C = (unsigned short*)Cout;
    #pragma unroll
    for (int f = 0; f < 8; ++f) {
      const int row = m0 + f * 16;
      #pragma unroll
      for (int g = 0; g < 4; ++g) {
        const int col = n0 + g * 16;
        float4 bv = *(const float4*)(bias + col);
        uint2 o;
        o.x = f2bf(acc[f][g][0] + bv.x) | ((uint32_t)f2bf(acc[f][g][1] + bv.y) << 16);
        o.y = f2bf(acc[f][g][2] + bv.z) | ((uint32_t)f2bf(acc[f][g][3] + bv.w) << 16);
        *(uint2*)(C + (size_t)row * N + col) = o;
      }
    }
  }
}

// ---------- reduce 4 f32 partials + bias -> out ----------
__global__ void reduce4_bias(const float* __restrict__ p,
                             const float* __restrict__ bo,
                             float* __restrict__ out) {
  const size_t S = (size_t)8192 * 512;
  size_t i = ((size_t)blockIdx.x * 256 + threadIdx.x) * 4;
  float4 a = *(const float4*)(p + i);
  float4 b = *(const float4*)(p + S + i);
  float4 c = *(const float4*)(p + 2 * S + i);
  float4 d = *(const float4*)(p + 3 * S + i);
  float4 bb = *(const float4*)(bo + (int)(i & 511));
  float4 o;
  o.x = a.x + b.x + c.x + d.x + bb.x;
  o.y = a.y + b.y + c.y + d.y + bb.y;
  o.z = a.z + b.z + c.z + d.z + bb.z;
  o.w = a.w + b.w + c.w + d.w + bb.w;
  *(float4*)(out + i) = o;
}

// ---------- MFMA energy + mask + softmax -> P (f32, 8192 x 64) ----------
// One wave per 2 tokens. 16x16 D = [tok0|tok1]-rows x [tok0|tok1]-cols; the two
// diagonal 8x8 blocks are the per-token energies.
__global__ __launch_bounds__(256) void energy_mfma(
    const unsigned short* __restrict__ Q,
    const unsigned short* __restrict__ Kb,
    const int* __restrict__ mask,
    float* __restrict__ P) {
  const int wave = threadIdx.x >> 6, ln = threadIdx.x & 63;
  const int t2 = (blockIdx.x * 4 + wave) * 2;          // first of 2 tokens
  const int r16 = ln & 15;                             // operand row/col index
  const int g = ln >> 4;                               // k-chunk group
  const size_t rowoff = (size_t)(t2 + (r16 >> 3)) * 4096 + (r16 & 7) * 512 + g * 8;
  const unsigned short* qb = Q + rowoff;
  const unsigned short* kb = Kb + rowoff;

  f32x4 acc = {};
  #pragma unroll
  for (int s = 0; s < 16; ++s) {
    bf16x8 qf = *(const bf16x8*)(qb + s * 32);
    bf16x8 kf = *(const bf16x8*)(kb + s * 32);
    acc = __builtin_amdgcn_mfma_f32_16x16x32_bf16(qf, kf, acc, 0, 0, 0);
  }

  // D: col = lane&15 (K index), row = g*4 + r (Q index). Valid iff same token.
  const int ct = r16 >> 3, j = r16 & 7;
  const bool valid = ((g >> 1) == ct);
  const int tok = t2 + ct;
  float pv[4];
  #pragma unroll
  for (int r = 0; r < 4; ++r) {
    const int i = (g & 1) * 4 + r;                     // Q head (valid lanes)
    float e = acc[r] * 0.044194173824159216f;          // 1/sqrt(512)
    int mk = 1;
    if (valid) mk = mask[(size_t)tok * 64 + i * 8 + j];
    if (mk == 0) e = -1e30f;
    float m = e;
    m = fmaxf(m, __shfl_xor(m, 1, 64));
    m = fmaxf(m, __shfl_xor(m, 2, 64));
    m = fmaxf(m, __shfl_xor(m, 4, 64));
    float p = __expf(e - m);
    float sum = p;
    sum += __shfl_xor(sum, 1, 64);
    sum += __shfl_xor(sum, 2, 64);
    sum += __shfl_xor(sum, 4, 64);
    pv[r] = p / sum;
  }
  if (valid) {
    #pragma unroll
    for (int r = 0; r < 4; ++r) {
      const int i = (g & 1) * 4 + r;
      P[(size_t)tok * 64 + i * 8 + j] = pv[r];
    }
  }
}

// ---------- PV: out2 rows in the (B,H,L,E)->(B,L,H*E) reshaped layout ----------
__global__ __launch_bounds__(256) void pv_kernel(
    const float* __restrict__ P,
    const unsigned short* __restrict__ Vb,
    unsigned short* __restrict__ out2) {
  const int wave = threadIdx.x >> 6, lane = threadIdx.x & 63;
  const int t = blockIdx.x * 4 + wave;
  const unsigned short* Vr = Vb + (size_t)t * 4096;
  float att = P[(size_t)t * 64 + lane];

  uint4 v4[8];
  #pragma unroll
  for (int jj = 0; jj < 8; ++jj)
    v4[jj] = *(const uint4*)(Vr + jj * 512 + lane * 8);

  const int nb = t >> 11, l = t & 2047;
  const size_t tok_base = (size_t)nb * 8388608 + (size_t)(l >> 3) * 4096 +
                          (size_t)(l & 7) * 512 + lane * 8;
  #pragma unroll
  for (int hh = 0; hh < 8; ++hh) {
    float accv[8] = {0.f, 0.f, 0.f, 0.f, 0.f, 0.f, 0.f, 0.f};
    #pragma unroll
    for (int jj = 0; jj < 8; ++jj) {
      float a = __shfl(att, hh * 8 + jj, 64);
      accv[0] += a * bflo(v4[jj].x); accv[1] += a * bfhi(v4[jj].x);
      accv[2] += a * bflo(v4[jj].y); accv[3] += a * bfhi(v4[jj].y);
      accv[4] += a * bflo(v4[jj].z); accv[5] += a * bfhi(v4[jj].z);
      accv[6] += a * bflo(v4[jj].w); accv[7] += a * bfhi(v4[jj].w);
    }
    uint4 o;
    o.x = f2bf(accv[0]) | ((uint32_t)f2bf(accv[1]) << 16);
    o.y = f2bf(accv[2]) | ((uint32_t)f2bf(accv[3]) << 16);
    o.z = f2bf(accv[4]) | ((uint32_t)f2bf(accv[5]) << 16);
    o.w = f2bf(accv[6]) | ((uint32_t)f2bf(accv[7]) << 16);
    *(uint4*)(out2 + tok_base + (size_t)hh * 1048576) = o;
  }
}

// ---------- launch ----------
extern "C" void kernel_launch(void* const* d_in, const int* in_sizes, int n_in,
                              void* d_out, int out_size, void* d_ws, size_t ws_size,
                              hipStream_t stream) {
  const float* values  = (const float*)d_in[0];
  const float* keys    = (const float*)d_in[1];
  const float* queries = (const float*)d_in[2];
  const int*   mask    = (const int*)d_in[3];
  const float* Wv = (const float*)d_in[4];
  const float* bv = (const float*)d_in[5];
  const float* Wk = (const float*)d_in[6];
  const float* bk = (const float*)d_in[7];
  const float* Wq = (const float*)d_in[8];
  const float* bq = (const float*)d_in[9];
  const float* Wo = (const float*)d_in[10];
  const float* bo = (const float*)d_in[11];

  unsigned short* xv  = (unsigned short*)d_ws;            // 8192*512 x3 (v,k,q)
  unsigned short* xk  = xv + 8192 * 512;
  unsigned short* xq  = xk + 8192 * 512;
  unsigned short* Wvt = xq + 8192 * 512;                  // 4096*512 x3 (v,k,q)
  unsigned short* Wkt = Wvt + 4096 * 512;
  unsigned short* Wqt = Wkt + 4096 * 512;
  unsigned short* Wot = Wqt + 4096 * 512;                 // 512*4096 (N x K)
  float*          P   = (float*)(Wot + 4096 * 512);       // 8192*64 f32
  unsigned short* bufA = (unsigned short*)(P + 8192 * 64); // 8192*4096 bf16
  unsigned short* bufB = bufA + (size_t)8192 * 4096;       // 8192*4096 bf16

  const int nx = 8192 * 512;
  cvt3_f32_bf16<<<dim3(nx / 8 / 256, 3), 256, 0, stream>>>(
      values, keys, queries, (uint32_t*)xv, nx);

  transpose3_to_bf16<<<dim3(4096 / 32, 512 / 32, 3), dim3(32, 8), 0, stream>>>(
      Wv, Wk, Wq, Wvt, 512, 4096);
  transpose_to_bf16<<<dim3(512 / 32, 4096 / 32), dim3(32, 8), 0, stream>>>(
      Wo, Wot, 4096, 512);

  // projections: M=8192, N=4096, K=512 -> Mt=32, Nt=16, KC=1, 512 blocks
  gemm256<8, false><<<512, 512, 0, stream>>>(xq, Wqt, bq, bufA, 32, 16, 1, 512);
  gemm256<8, false><<<512, 512, 0, stream>>>(xk, Wkt, bk, bufB, 32, 16, 1, 512);

  // energy + softmax -> P  (Q, K dead afterwards)
  energy_mfma<<<8192 / 8, 256, 0, stream>>>(bufA, bufB, mask, P);

  // V -> bufA (overwrites Q)
  gemm256<8, false><<<512, 512, 0, stream>>>(xv, Wvt, bv, bufA, 32, 16, 1, 512);

  // PV -> bufB (overwrites K)
  pv_kernel<<<8192 / 4, 256, 0, stream>>>(P, bufA, bufB);

  // final: split-K=4 f32 partials into bufA (exactly 67MB), then reduce+bias
  gemm256<16, true><<<256, 512, 0, stream>>>(bufB, Wot, nullptr, (float*)bufA,
                                             32, 2, 4, 4096);
  reduce4_bias<<<4096, 256, 0, stream>>>((float*)bufA, bo, (float*)d_out);
}

// Round 8
// 271.551 us; speedup vs baseline: 2.7264x; 1.0182x over previous
//
#include <hip/hip_runtime.h>
#include <stdint.h>

typedef __attribute__((ext_vector_type(4))) float f32x4;
typedef __attribute__((ext_vector_type(8))) __bf16 bf16x8;

// ---------- helpers ----------
__device__ __forceinline__ unsigned short f2bf(float f) {
  union { float f; uint32_t u; } v; v.f = f;
  uint32_t u = v.u;
  return (unsigned short)((u + 0x7FFFu + ((u >> 16) & 1u)) >> 16);
}
__device__ __forceinline__ float bflo(uint32_t u) {
  union { uint32_t u; float f; } v; v.u = u << 16; return v.f;
}
__device__ __forceinline__ float bfhi(uint32_t u) {
  union { uint32_t u; float f; } v; v.u = u & 0xffff0000u; return v.f;
}

__device__ __forceinline__ void async_copy16(void* lds, const void* g) {
  __builtin_amdgcn_global_load_lds(
      (const __attribute__((address_space(1))) void*)g,
      (__attribute__((address_space(3))) void*)lds,
      16, 0, 0);
}

// ---------- f32 -> bf16 convert: 3 tensors in one launch (blockIdx.y picks) ----------
__global__ void cvt3_f32_bf16(const float* __restrict__ in0,
                              const float* __restrict__ in1,
                              const float* __restrict__ in2,
                              uint32_t* __restrict__ out, int n) {
  const float* in = (blockIdx.y == 0) ? in0 : (blockIdx.y == 1) ? in1 : in2;
  uint32_t* o = out + (size_t)blockIdx.y * (n / 2);   // n bf16 = n/2 words
  int i = blockIdx.x * blockDim.x + threadIdx.x;
  int idx = i * 8;
  if (idx >= n) return;
  float4 a = *(const float4*)(in + idx);
  float4 b = *(const float4*)(in + idx + 4);
  uint4 ov;
  ov.x = f2bf(a.x) | ((uint32_t)f2bf(a.y) << 16);
  ov.y = f2bf(a.z) | ((uint32_t)f2bf(a.w) << 16);
  ov.z = f2bf(b.x) | ((uint32_t)f2bf(b.y) << 16);
  ov.w = f2bf(b.z) | ((uint32_t)f2bf(b.w) << 16);
  *(uint4*)(o + i * 4) = ov;
}

// ---------- f32 (R x C) -> bf16 transposed (C x R); gridDim.z picks tensor ----------
__global__ void transpose3_to_bf16(const float* __restrict__ in0,
                                   const float* __restrict__ in1,
                                   const float* __restrict__ in2,
                                   unsigned short* __restrict__ out,
                                   int R, int C) {
  const float* in = (blockIdx.z == 0) ? in0 : (blockIdx.z == 1) ? in1 : in2;
  unsigned short* o = out + (size_t)blockIdx.z * ((size_t)R * C);
  __shared__ float tile[32][33];
  int c0 = blockIdx.x * 32, r0 = blockIdx.y * 32;
  int tx = threadIdx.x, ty = threadIdx.y;   // 32 x 8
  #pragma unroll
  for (int rr = 0; rr < 32; rr += 8)
    tile[ty + rr][tx] = in[(size_t)(r0 + ty + rr) * C + c0 + tx];
  __syncthreads();
  #pragma unroll
  for (int rr = 0; rr < 32; rr += 8)
    o[(size_t)(c0 + ty + rr) * R + r0 + tx] = f2bf(tile[tx][ty + rr]);
}

__global__ void transpose_to_bf16(const float* __restrict__ in,
                                  unsigned short* __restrict__ out,
                                  int R, int C) {
  __shared__ float tile[32][33];
  int c0 = blockIdx.x * 32, r0 = blockIdx.y * 32;
  int tx = threadIdx.x, ty = threadIdx.y;
  #pragma unroll
  for (int rr = 0; rr < 32; rr += 8)
    tile[ty + rr][tx] = in[(size_t)(r0 + ty + rr) * C + c0 + tx];
  __syncthreads();
  #pragma unroll
  for (int rr = 0; rr < 32; rr += 8)
    out[(size_t)(c0 + ty + rr) * R + r0 + tx] = f2bf(tile[tx][ty + rr]);
}

// ---------- 256x256 8-wave GEMM, counted-vmcnt schedule, NN n-tiles/block ----------
// Each block: one M-panel (bm) x NN consecutive N-tiles (ng*NN..+NN-1), looping
// tau = 0..NN*NK-1 K-tiles with the double-buffer pipeline carried across the
// n-tile boundary. Per-n-tile epilogue inside the loop (after boundary barrier).
template <int NK, int NN, bool PARTIAL>
__global__ __launch_bounds__(512, 2) void gemm256(
    const unsigned short* __restrict__ A,
    const unsigned short* __restrict__ Bt,
    const float* __restrict__ bias,
    void* __restrict__ Cout,
    int Mt, int NtG, int KC, int Kfull) {
  constexpr int TT = NK * NN;
  static_assert(TT >= 3, "schedule needs >=3 tiles");
  __shared__ unsigned short lds[2 * 2 * 256 * 64];   // 131072 B

  const int nwg = Mt * NtG * KC;
  const int cpx = nwg >> 3;
  const int bid = blockIdx.x;
  const int nb = (bid & 7) * cpx + (bid >> 3);       // bijective XCD swizzle
  const int kc = nb / (Mt * NtG);
  const int r2 = nb % (Mt * NtG);
  const int bm = r2 / NtG;                           // consecutive nb share bm
  const int ng = r2 % NtG;
  const int N = NtG * NN * 256;
  const size_t koff = (size_t)kc * (NK * 64);

  const int tid = threadIdx.x;
  const int wv = tid >> 6, ln = tid & 63;
  const int wm = wv >> 2, wn = wv & 3;     // 2 M-waves x 4 N-waves

  f32x4 acc[8][4] = {};
  bf16x8 af[4][2];
  bf16x8 bfb[2][2];

  auto stage_A = [&](int h, int tau) {
    const int kt = tau % NK;
    #pragma unroll
    for (int r = 0; r < 2; ++r) {
      const int rb = r * 128 + h * 64 + wv * 8;
      const int row = rb + (ln >> 3);
      const int kcs = (ln & 7) ^ (row & 7);
      const unsigned short* g =
          A + (size_t)(bm * 256 + row) * Kfull + koff + kt * 64 + kcs * 8;
      char* dst = (char*)lds + (size_t)(tau & 1) * 65536 + rb * 128;
      async_copy16(dst, g);
    }
  };
  auto stage_B = [&](int h, int tau) {
    const int kt = tau % NK;
    const int bnn = ng * NN + tau / NK;
    #pragma unroll
    for (int r = 0; r < 2; ++r) {
      const int s = r * 2 + (wv >> 2);
      const int rb = s * 64 + h * 32 + (wv & 3) * 8;
      const int row = rb + (ln >> 3);
      const int kcs = (ln & 7) ^ (row & 7);
      const unsigned short* g =
          Bt + (size_t)(bnn * 256 + row) * Kfull + koff + kt * 64 + kcs * 8;
      char* dst = (char*)lds + (size_t)(tau & 1) * 65536 + 32768 + rb * 128;
      async_copy16(dst, g);
    }
  };
  auto load_af = [&](int mh, const char* buf) {
    #pragma unroll
    for (int f = 0; f < 4; ++f) {
      const int lr = wm * 128 + (mh * 4 + f) * 16 + (ln & 15);
      #pragma unroll
      for (int s = 0; s < 2; ++s) {
        const int kq = s * 4 + (ln >> 4);
        af[f][s] = *(const bf16x8*)(buf + lr * 128 + ((kq ^ (lr & 7)) * 16));
      }
    }
  };
  auto load_bf = [&](int nh, const char* buf) {
    #pragma unroll
    for (int gq = 0; gq < 2; ++gq) {
      const int lr = wn * 64 + (nh * 2 + gq) * 16 + (ln & 15);
      #pragma unroll
      for (int s = 0; s < 2; ++s) {
        const int kq = s * 4 + (ln >> 4);
        bfb[gq][s] =
            *(const bf16x8*)(buf + 32768 + lr * 128 + ((kq ^ (lr & 7)) * 16));
      }
    }
  };
  auto mfma_quad = [&](int mh, int nh) {
    __builtin_amdgcn_sched_barrier(0);
    __builtin_amdgcn_s_barrier();
    __builtin_amdgcn_sched_barrier(0);
    __builtin_amdgcn_s_setprio(1);
    #pragma unroll
    for (int f = 0; f < 4; ++f)
      #pragma unroll
      for (int gq = 0; gq < 2; ++gq)
        #pragma unroll
        for (int s = 0; s < 2; ++s)
          acc[mh * 4 + f][nh * 2 + gq] = __builtin_amdgcn_mfma_f32_16x16x32_bf16(
              bfb[gq][s], af[f][s], acc[mh * 4 + f][nh * 2 + gq], 0, 0, 0);
    __builtin_amdgcn_s_setprio(0);
    __builtin_amdgcn_sched_barrier(0);
  };
  auto epilogue = [&](int nt) {
    const int m0 = bm * 256 + wm * 128 + (ln & 15);
    const int n0 = (ng * NN + nt) * 256 + wn * 64 + ((ln >> 4) << 2);
    if (PARTIAL) {
      float* Cp = (float*)Cout + (size_t)kc * ((size_t)Mt * 256) * N;
      #pragma unroll
      for (int f = 0; f < 8; ++f) {
        const int row = m0 + f * 16;
        #pragma unroll
        for (int g = 0; g < 4; ++g)
          *(f32x4*)(Cp + (size_t)row * N + n0 + g * 16) = acc[f][g];
      }
    } else {
      unsigned short* C = (unsigned short*)Cout;
      #pragma unroll
      for (int f = 0; f < 8; ++f) {
        const int row = m0 + f * 16;
        #pragma unroll
        for (int g = 0; g < 4; ++g) {
          const int col = n0 + g * 16;
          float4 bv = *(const float4*)(bias + col);
          uint2 o;
          o.x = f2bf(acc[f][g][0] + bv.x) | ((uint32_t)f2bf(acc[f][g][1] + bv.y) << 16);
          o.y = f2bf(acc[f][g][2] + bv.z) | ((uint32_t)f2bf(acc[f][g][3] + bv.w) << 16);
          *(uint2*)(C + (size_t)row * N + col) = o;
        }
      }
    }
    #pragma unroll
    for (int f = 0; f < 8; ++f)
      #pragma unroll
      for (int g = 0; g < 4; ++g)
        acc[f][g] = (f32x4){0.f, 0.f, 0.f, 0.f};
  };

  // prologue: tile 0 halves h0..h3, tile 1 halves h0..h2 (7 halves, 14 loads)
  stage_A(0, 0); stage_B(1, 0); stage_A(1, 0); stage_B(0, 0);
  stage_A(0, 1); stage_B(1, 1); stage_A(1, 1);
  asm volatile("s_waitcnt vmcnt(6)" ::: "memory");
  __builtin_amdgcn_sched_barrier(0);
  __builtin_amdgcn_s_barrier();

  for (int tau = 0; tau < TT; ++tau) {
    const char* buf = (const char*)lds + (size_t)(tau & 1) * 65536;
    load_af(0, buf); load_bf(0, buf);
    if (tau + 1 < TT) stage_B(0, tau + 1);
    mfma_quad(0, 0);
    __builtin_amdgcn_s_barrier();
    load_bf(1, buf);
    if (tau + 2 < TT) stage_A(0, tau + 2);
    mfma_quad(0, 1);
    __builtin_amdgcn_s_barrier();
    load_af(1, buf);
    if (tau + 2 < TT) stage_B(1, tau + 2);
    mfma_quad(1, 1);
    __builtin_amdgcn_s_barrier();
    load_bf(0, buf);
    if (tau + 2 < TT) stage_A(1, tau + 2);
    mfma_quad(1, 0);
    if (tau + 2 < TT) {
      asm volatile("s_waitcnt vmcnt(6)" ::: "memory");
    } else if (tau + 1 < TT) {
      asm volatile("s_waitcnt vmcnt(0)" ::: "memory");
    }
    __builtin_amdgcn_sched_barrier(0);
    __builtin_amdgcn_s_barrier();
    // finished an n-tile? write it (overlaps next tile's ds_reads) + reset acc
    if ((tau + 1) % NK == 0) epilogue(tau / NK);
  }
}

// ---------- reduce 4 f32 partials + bias -> out ----------
__global__ void reduce4_bias(const float* __restrict__ p,
                             const float* __restrict__ bo,
                             float* __restrict__ out) {
  const size_t S = (size_t)8192 * 512;
  size_t i = ((size_t)blockIdx.x * 256 + threadIdx.x) * 4;
  float4 a = *(const float4*)(p + i);
  float4 b = *(const float4*)(p + S + i);
  float4 c = *(const float4*)(p + 2 * S + i);
  float4 d = *(const float4*)(p + 3 * S + i);
  float4 bb = *(const float4*)(bo + (int)(i & 511));
  float4 o;
  o.x = a.x + b.x + c.x + d.x + bb.x;
  o.y = a.y + b.y + c.y + d.y + bb.y;
  o.z = a.z + b.z + c.z + d.z + bb.z;
  o.w = a.w + b.w + c.w + d.w + bb.w;
  *(float4*)(out + i) = o;
}

// ---------- MFMA energy + mask + softmax -> P (f32, 8192 x 64) ----------
__global__ __launch_bounds__(256) void energy_mfma(
    const unsigned short* __restrict__ Q,
    const unsigned short* __restrict__ Kb,
    const int* __restrict__ mask,
    float* __restrict__ P) {
  const int wave = threadIdx.x >> 6, ln = threadIdx.x & 63;
  const int t2 = (blockIdx.x * 4 + wave) * 2;          // first of 2 tokens
  const int r16 = ln & 15;                             // operand row/col index
  const int g = ln >> 4;                               // k-chunk group
  const size_t rowoff = (size_t)(t2 + (r16 >> 3)) * 4096 + (r16 & 7) * 512 + g * 8;
  const unsigned short* qb = Q + rowoff;
  const unsigned short* kb = Kb + rowoff;

  f32x4 acc = {};
  #pragma unroll
  for (int s = 0; s < 16; ++s) {
    bf16x8 qf = *(const bf16x8*)(qb + s * 32);
    bf16x8 kf = *(const bf16x8*)(kb + s * 32);
    acc = __builtin_amdgcn_mfma_f32_16x16x32_bf16(qf, kf, acc, 0, 0, 0);
  }

  const int ct = r16 >> 3, j = r16 & 7;
  const bool valid = ((g >> 1) == ct);
  const int tok = t2 + ct;
  float pv[4];
  #pragma unroll
  for (int r = 0; r < 4; ++r) {
    const int i = (g & 1) * 4 + r;
    float e = acc[r] * 0.044194173824159216f;          // 1/sqrt(512)
    int mk = 1;
    if (valid) mk = mask[(size_t)tok * 64 + i * 8 + j];
    if (mk == 0) e = -1e30f;
    float m = e;
    m = fmaxf(m, __shfl_xor(m, 1, 64));
    m = fmaxf(m, __shfl_xor(m, 2, 64));
    m = fmaxf(m, __shfl_xor(m, 4, 64));
    float p = __expf(e - m);
    float sum = p;
    sum += __shfl_xor(sum, 1, 64);
    sum += __shfl_xor(sum, 2, 64);
    sum += __shfl_xor(sum, 4, 64);
    pv[r] = p / sum;
  }
  if (valid) {
    #pragma unroll
    for (int r = 0; r < 4; ++r) {
      const int i = (g & 1) * 4 + r;
      P[(size_t)tok * 64 + i * 8 + j] = pv[r];
    }
  }
}

// ---------- PV: out2 rows in the (B,H,L,E)->(B,L,H*E) reshaped layout ----------
__global__ __launch_bounds__(256) void pv_kernel(
    const float* __restrict__ P,
    const unsigned short* __restrict__ Vb,
    unsigned short* __restrict__ out2) {
  const int wave = threadIdx.x >> 6, lane = threadIdx.x & 63;
  const int t = blockIdx.x * 4 + wave;
  const unsigned short* Vr = Vb + (size_t)t * 4096;
  float att = P[(size_t)t * 64 + lane];

  uint4 v4[8];
  #pragma unroll
  for (int jj = 0; jj < 8; ++jj)
    v4[jj] = *(const uint4*)(Vr + jj * 512 + lane * 8);

  const int nb = t >> 11, l = t & 2047;
  const size_t tok_base = (size_t)nb * 8388608 + (size_t)(l >> 3) * 4096 +
                          (size_t)(l & 7) * 512 + lane * 8;
  #pragma unroll
  for (int hh = 0; hh < 8; ++hh) {
    float accv[8] = {0.f, 0.f, 0.f, 0.f, 0.f, 0.f, 0.f, 0.f};
    #pragma unroll
    for (int jj = 0; jj < 8; ++jj) {
      float a = __shfl(att, hh * 8 + jj, 64);
      accv[0] += a * bflo(v4[jj].x); accv[1] += a * bfhi(v4[jj].x);
      accv[2] += a * bflo(v4[jj].y); accv[3] += a * bfhi(v4[jj].y);
      accv[4] += a * bflo(v4[jj].z); accv[5] += a * bfhi(v4[jj].z);
      accv[6] += a * bflo(v4[jj].w); accv[7] += a * bfhi(v4[jj].w);
    }
    uint4 o;
    o.x = f2bf(accv[0]) | ((uint32_t)f2bf(accv[1]) << 16);
    o.y = f2bf(accv[2]) | ((uint32_t)f2bf(accv[3]) << 16);
    o.z = f2bf(accv[4]) | ((uint32_t)f2bf(accv[5]) << 16);
    o.w = f2bf(accv[6]) | ((uint32_t)f2bf(accv[7]) << 16);
    *(uint4*)(out2 + tok_base + (size_t)hh * 1048576) = o;
  }
}

// ---------- launch ----------
extern "C" void kernel_launch(void* const* d_in, const int* in_sizes, int n_in,
                              void* d_out, int out_size, void* d_ws, size_t ws_size,
                              hipStream_t stream) {
  const float* values  = (const float*)d_in[0];
  const float* keys    = (const float*)d_in[1];
  const float* queries = (const float*)d_in[2];
  const int*   mask    = (const int*)d_in[3];
  const float* Wv = (const float*)d_in[4];
  const float* bv = (const float*)d_in[5];
  const float* Wk = (const float*)d_in[6];
  const float* bk = (const float*)d_in[7];
  const float* Wq = (const float*)d_in[8];
  const float* bq = (const float*)d_in[9];
  const float* Wo = (const float*)d_in[10];
  const float* bo = (const float*)d_in[11];

  unsigned short* xv  = (unsigned short*)d_ws;            // 8192*512 x3 (v,k,q)
  unsigned short* xk  = xv + 8192 * 512;
  unsigned short* xq  = xk + 8192 * 512;
  unsigned short* Wvt = xq + 8192 * 512;                  // 4096*512 x3 (v,k,q)
  unsigned short* Wkt = Wvt + 4096 * 512;
  unsigned short* Wqt = Wkt + 4096 * 512;
  unsigned short* Wot = Wqt + 4096 * 512;                 // 512*4096 (N x K)
  float*          P   = (float*)(Wot + 4096 * 512);       // 8192*64 f32
  unsigned short* bufA = (unsigned short*)(P + 8192 * 64); // 8192*4096 bf16
  unsigned short* bufB = bufA + (size_t)8192 * 4096;       // 8192*4096 bf16

  const int nx = 8192 * 512;
  cvt3_f32_bf16<<<dim3(nx / 8 / 256, 3), 256, 0, stream>>>(
      values, keys, queries, (uint32_t*)xv, nx);

  transpose3_to_bf16<<<dim3(4096 / 32, 512 / 32, 3), dim3(32, 8), 0, stream>>>(
      Wv, Wk, Wq, Wvt, 512, 4096);
  transpose_to_bf16<<<dim3(512 / 32, 4096 / 32), dim3(32, 8), 0, stream>>>(
      Wo, Wot, 4096, 512);

  // projections: M=8192, N=4096, K=512 -> Mt=32, NtG=8, NN=2, 256 blocks (1 round)
  gemm256<8, 2, false><<<256, 512, 0, stream>>>(xq, Wqt, bq, bufA, 32, 8, 1, 512);
  gemm256<8, 2, false><<<256, 512, 0, stream>>>(xk, Wkt, bk, bufB, 32, 8, 1, 512);

  // energy + softmax -> P  (Q, K dead afterwards)
  energy_mfma<<<8192 / 8, 256, 0, stream>>>(bufA, bufB, mask, P);

  // V -> bufA (overwrites Q)
  gemm256<8, 2, false><<<256, 512, 0, stream>>>(xv, Wvt, bv, bufA, 32, 8, 1, 512);

  // PV -> bufB (overwrites K)
  pv_kernel<<<8192 / 4, 256, 0, stream>>>(P, bufA, bufB);

  // final: split-K=4 f32 partials into bufA (exactly 67MB), then reduce+bias
  gemm256<16, 1, true><<<256, 512, 0, stream>>>(bufB, Wot, nullptr, (float*)bufA,
                                                32, 2, 4, 4096);
  reduce4_bias<<<4096, 256, 0, stream>>>((float*)bufA, bo, (float*)d_out);
}